// Round 15
// baseline (279.346 us; speedup 1.0000x reference)
//
#include <hip/hip_runtime.h>
#include <hip/hip_bf16.h>
#include <cstdint>
#include <cstddef>

#define TOK 8192
#define DIM 1024
#define FF  2048
#define NE  8
#define MAXTILES 72        // 128-row m-tile slots: 64 + 8 partials
#define NBLK 32            // count_rank blocks (256 tokens each)

typedef __attribute__((ext_vector_type(8))) short short8;
typedef __attribute__((ext_vector_type(4))) float f32x4;

__device__ inline void gload_lds16(const void* g, void* l) {
  __builtin_amdgcn_global_load_lds(
      (const __attribute__((address_space(1))) unsigned int*)g,
      (__attribute__((address_space(3))) unsigned int*)l, 16, 0, 0);
}

__device__ inline unsigned short f2bf(float f) {
  unsigned int u = __float_as_uint(f);
  u += 0x7fffu + ((u >> 16) & 1u);   // RNE
  return (unsigned short)(u >> 16);
}
__device__ inline float bf2f(unsigned short u) {
  return __uint_as_float(((unsigned int)u) << 16);
}
__device__ inline unsigned int cvt_pk_bf16(float a, float b) {  // lo=bf16(a), hi=bf16(b), RNE
  unsigned int r;
  asm("v_cvt_pk_bf16_f32 %0, %1, %2" : "=v"(r) : "v"(a), "v"(b));
  return r;
}

// ---------------- weight fp32 -> bf16 (W2 only; W1 converts inside gemm1) -----------
__global__ __launch_bounds__(256) void convert_kernel(
    const float* __restrict__ src, unsigned short* __restrict__ dst, int n) {
  const int stride = gridDim.x * blockDim.x * 4;
  for (int i = (blockIdx.x * blockDim.x + threadIdx.x) * 4; i < n; i += stride) {
    const float4 v = *reinterpret_cast<const float4*>(src + i);
    ushort4 o;
    o.x = f2bf(v.x); o.y = f2bf(v.y); o.z = f2bf(v.z); o.w = f2bf(v.w);
    *reinterpret_cast<ushort4*>(dst + i) = o;
  }
}

// ---------------- gating: logits, top-2 (highest index wins) -- no atomics ----------
__global__ __launch_bounds__(256) void gate_kernel(
    const float* __restrict__ x, const float* __restrict__ Wg,
    const float* __restrict__ bg, int* __restrict__ assign) {
  const int token = blockIdx.x * 4 + (threadIdx.x >> 6);
  const int lane = threadIdx.x & 63;
  if (token >= TOK) return;
  const float* xr = x + (size_t)token * DIM;
  float acc[NE];
#pragma unroll
  for (int e = 0; e < NE; ++e) acc[e] = 0.f;
#pragma unroll
  for (int i0 = 0; i0 < DIM; i0 += 256) {
    const int i = i0 + lane * 4;
    const float4 xv = *reinterpret_cast<const float4*>(xr + i);
#pragma unroll
    for (int e = 0; e < NE; ++e) {
      const float4 wv = *reinterpret_cast<const float4*>(Wg + e * DIM + i);
      acc[e] += xv.x * wv.x + xv.y * wv.y + xv.z * wv.z + xv.w * wv.w;
    }
  }
#pragma unroll
  for (int e = 0; e < NE; ++e) {
    float v = acc[e];
#pragma unroll
    for (int s = 32; s; s >>= 1) v += __shfl_xor(v, s);
    acc[e] = v + bg[e];
  }
  if (lane == 0) {
    float v1 = -INFINITY, v2 = -INFINITY; int i1 = 0, i2 = 0;
#pragma unroll
    for (int e = 0; e < NE; ++e) {
      const float v = acc[e];
      if (v > v1)      { v2 = v1; i2 = i1; v1 = v; i1 = e; }
      else if (v > v2) { v2 = v; i2 = e; }
    }
    assign[token] = (i1 > i2) ? i1 : i2;  // max(top2 indices); softmax-sum weight == 1.0
  }
}

// ---------------- ballot-based per-block counts + in-block ranks (no atomics) -------
__global__ __launch_bounds__(256) void count_rank_kernel(
    const int* __restrict__ assign, int* __restrict__ rank,
    int* __restrict__ blkcnt) {
  const int blk = blockIdx.x;
  const int tid = threadIdx.x;
  const int t = blk * 256 + tid;
  const int lane = tid & 63, wave = tid >> 6;
  const int a = assign[t];
  __shared__ int wcnt[4][NE];
  int myrank = 0;
#pragma unroll
  for (int e = 0; e < NE; ++e) {
    const unsigned long long m = __ballot(a == e);
    if (a == e) myrank = __popcll(m & ((1ull << lane) - 1ull));
    if (lane == 0) wcnt[wave][e] = __popcll(m);
  }
  __syncthreads();
  int pre = 0;
  for (int w = 0; w < wave; ++w) pre += wcnt[w][a];
  rank[t] = pre + myrank;
  if (tid < NE)
    blkcnt[blk * NE + tid] = wcnt[0][tid] + wcnt[1][tid] + wcnt[2][tid] + wcnt[3][tid];
}

// ---------------- scan: block offsets, expert offsets, 128-row tile table -----------
// ctrl: [16..24]=offsets, [25]=ntiles, [32..103]=tile_e, [128..199]=tile_m
__global__ void scan2_kernel(int* __restrict__ ctrl, const int* __restrict__ blkcnt,
                             int* __restrict__ blkoff) {
  const int tid = threadIdx.x;
  __shared__ int ecnt[NE];
  if (tid < NE) {
    int run = 0;
    for (int b = 0; b < NBLK; ++b) {
      blkoff[b * NE + tid] = run;
      run += blkcnt[b * NE + tid];
    }
    ecnt[tid] = run;
  }
  __syncthreads();
  if (tid == 0) {
    int s = 0, nt = 0;
#pragma unroll
    for (int e = 0; e < NE; ++e) {
      ctrl[16 + e] = s;
      const int cnt = ecnt[e];
      for (int m = 0; m * 128 < cnt && nt < MAXTILES; ++m) {
        ctrl[32 + nt] = e;  ctrl[128 + nt] = m;  ++nt;
      }
      s += cnt;
    }
    ctrl[24] = s;
    ctrl[25] = nt;
  }
  __syncthreads();
  if (tid < NE) {
    const int off = ctrl[16 + tid];
    for (int b = 0; b < NBLK; ++b) blkoff[b * NE + tid] += off;
  }
}

// ---------------- gather tokens into expert-contiguous bf16 rows (no atomics) -------
__global__ __launch_bounds__(256) void gather_kernel(
    const float* __restrict__ x, const int* __restrict__ assign,
    const int* __restrict__ rank, const int* __restrict__ blkoff,
    int* __restrict__ ridx, unsigned short* __restrict__ Xb) {
  const int token = blockIdx.x;
  const int a = assign[token];
  const int row = blkoff[(token >> 8) * NE + a] + rank[token];
  if (threadIdx.x == 0) ridx[row] = token;
  const int j = threadIdx.x * 4;
  const float4 v = *reinterpret_cast<const float4*>(x + (size_t)token * DIM + j);
  ushort4 o;
  o.x = f2bf(v.x); o.y = f2bf(v.y); o.z = f2bf(v.z); o.w = f2bf(v.w);
  *reinterpret_cast<ushort4*>(Xb + (size_t)row * DIM + j) = o;
}

// ================= grouped GEMM1: H = Xb @ W1e^T + b1 (bf16 out) =====================
// r12 form: 128x128xBK64, 512 thr / 8 waves (2Mx4N). A: bf16 gload_lds, dbuf.
// B: fp32 W1 reg-staged + fused cvt_pk->bf16 + swizzled ds_write (no convert kernel).
__global__ __launch_bounds__(512) void gemm1_kernel(
    const unsigned short* __restrict__ Xb, const float* __restrict__ W1,
    const float* __restrict__ b1, const int* __restrict__ ctrl,
    unsigned short* __restrict__ Hb) {
  const int b = blockIdx.x;
  const int lid = (b & 7) * (16 * MAXTILES / 8) + (b >> 3);  // XCD-chunked, bijective
  const int nx = lid / MAXTILES;            // ti-fastest: same-XCD blocks share B panels
  const int ti = lid % MAXTILES;
  if (ti >= ctrl[25]) return;
  const int e = ctrl[32 + ti];
  const int m_tile = ctrl[128 + ti];
  const int base = ctrl[16 + e];
  const int count = ctrl[17 + e] - base;
  const int n0 = nx * 128;
  constexpr int K = DIM, NT = DIM / 64;
  __shared__ unsigned short As[2][8192];    // 2 x 16KB
  __shared__ unsigned short Bs[8192];       // 16KB (single: write/read barrier-separated)
  const int tid = threadIdx.x;
  const int wave = tid >> 6, lane = tid & 63;
  const int wm = wave >> 2, wn = wave & 3;
  const int l15 = lane & 15, l7 = lane & 7, jb = lane >> 4, arow = lane >> 3;
  const int acolS = (l7 ^ arow) * 8;        // A pre-swizzled source col (T2 + rule#21)
  f32x4 acc[4][2] = {};
  const unsigned short* Ag = Xb + (size_t)(base + m_tile * 128) * K;
  const float* Bg = W1 + ((size_t)e * FF + n0) * K;
  const int maxr = (TOK - 1) - (base + m_tile * 128);
  const int c0 = tid, c1 = tid + 512;
  const int r0 = c0 >> 3, j0 = c0 & 7, r1 = c1 >> 3, j1 = c1 & 7;
  const int wr0 = (r0 * 64 + (j0 ^ (r0 & 7)) * 8);   // swizzled LDS dest (shorts)
  const int wr1 = (r1 * 64 + (j1 ^ (r1 & 7)) * 8);
  const float* bp0 = Bg + (size_t)r0 * K + j0 * 8;
  const float* bp1 = Bg + (size_t)r1 * K + j1 * 8;
  float4 br0[4], br1[4];                     // 2 reg sets, ping-pong (static idx)

  auto gloadA = [&](int buf, int t) {
#pragma unroll
    for (int it = 0; it < 2; ++it) {
      const int c = it * 8 + wave;
      int r = c * 8 + arow; if (r > maxr) r = maxr;
      gload_lds16(Ag + (size_t)r * K + t * 64 + acolS, &As[buf][c * 512]);
    }
  };
  auto loadB = [&](float4 (&br)[4], int t) {
    br[0] = *reinterpret_cast<const float4*>(bp0 + t * 64);
    br[1] = *reinterpret_cast<const float4*>(bp0 + t * 64 + 4);
    br[2] = *reinterpret_cast<const float4*>(bp1 + t * 64);
    br[3] = *reinterpret_cast<const float4*>(bp1 + t * 64 + 4);
  };
  auto writeB = [&](float4 (&br)[4]) {
    uint4 p;
    p.x = cvt_pk_bf16(br[0].x, br[0].y); p.y = cvt_pk_bf16(br[0].z, br[0].w);
    p.z = cvt_pk_bf16(br[1].x, br[1].y); p.w = cvt_pk_bf16(br[1].z, br[1].w);
    *reinterpret_cast<uint4*>(&Bs[wr0]) = p;
    p.x = cvt_pk_bf16(br[2].x, br[2].y); p.y = cvt_pk_bf16(br[2].z, br[2].w);
    p.z = cvt_pk_bf16(br[3].x, br[3].y); p.w = cvt_pk_bf16(br[3].z, br[3].w);
    *reinterpret_cast<uint4*>(&Bs[wr1]) = p;
  };
  auto compute = [&](int buf) {
#pragma unroll
    for (int kk = 0; kk < 64; kk += 32) {
      short8 a[4], bb[2];
      const int js = (((kk >> 3) + jb) ^ l7) << 3;
#pragma unroll
      for (int i = 0; i < 4; ++i)
        a[i] = *reinterpret_cast<const short8*>(&As[buf][(wm * 64 + i * 16 + l15) * 64 + js]);
#pragma unroll
      for (int j = 0; j < 2; ++j)
        bb[j] = *reinterpret_cast<const short8*>(&Bs[(wn * 32 + j * 16 + l15) * 64 + js]);
#pragma unroll
      for (int i = 0; i < 4; ++i)
#pragma unroll
        for (int j = 0; j < 2; ++j)
          acc[i][j] = __builtin_amdgcn_mfma_f32_16x16x32_bf16(a[i], bb[j], acc[i][j], 0, 0, 0);
    }
  };
  auto phase = [&](float4 (&brC)[4], float4 (&brN)[4], int buf, int t) {
    const int t1 = (t + 1 < NT) ? t + 1 : 0;   // wrap: dead re-stage
    gloadA(buf ^ 1, t1);
    writeB(brC);
    loadB(brN, t1);
    asm volatile("s_waitcnt vmcnt(6) lgkmcnt(0)" ::: "memory");
    __builtin_amdgcn_sched_barrier(0);
    __builtin_amdgcn_s_barrier();
    __builtin_amdgcn_sched_barrier(0);
    compute(buf);
    __builtin_amdgcn_sched_barrier(0);
    __builtin_amdgcn_s_barrier();
    __builtin_amdgcn_sched_barrier(0);
  };

  loadB(br0, 0);        // queue: B(0)x4 ...
  gloadA(0, 0);         // ... then A(0)x2
#pragma unroll 1
  for (int t = 0; t < NT; t += 2) {
    phase(br0, br1, 0, t);
    phase(br1, br0, 1, t + 1);
  }

  const float* b1e = b1 + (size_t)e * FF;
  const int rbase = m_tile * 128 + wm * 64 + (lane >> 4) * 4;
  const int cbase = n0 + wn * 32 + l15;
#pragma unroll
  for (int i = 0; i < 4; ++i) {
#pragma unroll
    for (int j = 0; j < 2; ++j) {
      const int col = cbase + j * 16;
      const float bias = b1e[col];
#pragma unroll
      for (int r = 0; r < 4; ++r) {
        const int lr = rbase + i * 16 + r;
        if (lr < count)
          Hb[(size_t)(base + lr) * FF + col] = f2bf(acc[i][j][r] + bias);
      }
    }
  }
}

// ---------------- LayerNorm + exact GELU, in place on Hb ----------------
__global__ __launch_bounds__(256) void ln_gelu_kernel(
    unsigned short* __restrict__ Hb, const float* __restrict__ ln_g,
    const float* __restrict__ ln_b, const int* __restrict__ offsets) {
  const int row = blockIdx.x;
  int e = 0;
#pragma unroll
  for (int i = 1; i < NE; ++i) e += (row >= offsets[i]) ? 1 : 0;
  unsigned short* h = Hb + (size_t)row * FF;
  const int tid = threadIdx.x;
  const int lane = tid & 63, wave = tid >> 6;
  float v[8];
  float sum = 0.f, sq = 0.f;
  short8 raw = *reinterpret_cast<const short8*>(h + tid * 8);
#pragma unroll
  for (int i = 0; i < 8; ++i) {
    v[i] = bf2f((unsigned short)raw[i]);
    sum += v[i]; sq += v[i] * v[i];
  }
#pragma unroll
  for (int s = 32; s; s >>= 1) { sum += __shfl_xor(sum, s); sq += __shfl_xor(sq, s); }
  __shared__ float red[8];
  if (lane == 0) { red[wave] = sum; red[wave + 4] = sq; }
  __syncthreads();
  sum = red[0] + red[1] + red[2] + red[3];
  sq  = red[4] + red[5] + red[6] + red[7];
  const float mu = sum * (1.f / FF);
  const float var = sq * (1.f / FF) - mu * mu;
  const float rstd = rsqrtf(var + 1e-5f);
  const float* ge = ln_g + (size_t)e * FF + tid * 8;
  const float* be = ln_b + (size_t)e * FF + tid * 8;
  short8 outv;
#pragma unroll
  for (int i = 0; i < 8; ++i) {
    const float t = (v[i] - mu) * rstd * ge[i] + be[i];
    const float g = 0.5f * t * (1.f + erff(t * 0.70710678118f));
    outv[i] = (short)f2bf(g);
  }
  *reinterpret_cast<short8*>(h + tid * 8) = outv;
}

// ================= grouped GEMM2: out[t] = (Hb @ W2e^T + b2)*se + x[t] ===============
// r11's best measured form (91us): 128x128 8-wave, bf16 B via gload_lds, single-buffer
// 32KB, 2-sync loop, XCD-chunked ti-fastest grid.
__global__ __launch_bounds__(512) void gemm2_kernel(
    const unsigned short* __restrict__ Hb, const unsigned short* __restrict__ W2b,
    const float* __restrict__ b2, const float* __restrict__ res_scale,
    const int* __restrict__ ctrl, const int* __restrict__ ridx,
    const float* __restrict__ x, float* __restrict__ out) {
  const int b = blockIdx.x;
  const int lid = (b & 7) * MAXTILES + (b >> 3);   // grid 8*MAXTILES
  const int nx = lid / MAXTILES;
  const int ti = lid % MAXTILES;
  if (ti >= ctrl[25]) return;
  const int e = ctrl[32 + ti];
  const int m_tile = ctrl[128 + ti];
  const int base = ctrl[16 + e];
  const int count = ctrl[17 + e] - base;
  const int n0 = nx * 128;
  constexpr int K = FF;
  __shared__ unsigned short As[128 * 64];
  __shared__ unsigned short Bs[128 * 64];
  const int tid = threadIdx.x;
  const int wave = tid >> 6, lane = tid & 63;
  const int wm = wave >> 2, wn = wave & 3;
  const int l15 = lane & 15, l7 = lane & 7, jb = lane >> 4, arow = lane >> 3;
  const int acolS = (l7 ^ arow) * 8;
  f32x4 acc[4][2] = {};
  const unsigned short* Ag = Hb + (size_t)(base + m_tile * 128) * K;
  const unsigned short* Bg = W2b + ((size_t)e * DIM + n0) * K;
  const int maxr = (TOK - 1) - (base + m_tile * 128);
  for (int k0 = 0; k0 < K; k0 += 64) {
    __syncthreads();
#pragma unroll
    for (int it = 0; it < 2; ++it) {
      const int c = it * 8 + wave;
      int r = c * 8 + arow; if (r > maxr) r = maxr;
      gload_lds16(Ag + (size_t)r * K + k0 + acolS, &As[c * 512]);
      gload_lds16(Bg + (size_t)(c * 8 + arow) * K + k0 + acolS, &Bs[c * 512]);
    }
    __syncthreads();
#pragma unroll
    for (int kk = 0; kk < 64; kk += 32) {
      short8 a[4], bb[2];
      const int js = (((kk >> 3) + jb) ^ l7) << 3;
#pragma unroll
      for (int i = 0; i < 4; ++i)
        a[i] = *reinterpret_cast<const short8*>(
            &As[(wm * 64 + i * 16 + l15) * 64 + js]);
#pragma unroll
      for (int j = 0; j < 2; ++j)
        bb[j] = *reinterpret_cast<const short8*>(
            &Bs[(wn * 32 + j * 16 + l15) * 64 + js]);
#pragma unroll
      for (int i = 0; i < 4; ++i)
#pragma unroll
        for (int j = 0; j < 2; ++j)
          acc[i][j] = __builtin_amdgcn_mfma_f32_16x16x32_bf16(a[i], bb[j], acc[i][j], 0, 0, 0);
    }
  }
  const float* b2e = b2 + (size_t)e * DIM;
  const float se = res_scale[e];
  const int rbase = m_tile * 128 + wm * 64 + (lane >> 4) * 4;
  const int cbase = n0 + wn * 32 + l15;
#pragma unroll
  for (int i = 0; i < 4; ++i) {
#pragma unroll
    for (int r = 0; r < 4; ++r) {
      const int lr = rbase + i * 16 + r;
      if (lr < count) {
        const int trow = ridx[base + lr];
        const float* xrow = x + (size_t)trow * DIM;
        float* orow = out + (size_t)trow * DIM;
#pragma unroll
        for (int j = 0; j < 2; ++j) {
          const int col = cbase + j * 16;
          orow[col] = (acc[i][j][r] + b2e[col]) * se + xrow[col];
        }
      }
    }
  }
}

extern "C" void kernel_launch(void* const* d_in, const int* in_sizes, int n_in,
                              void* d_out, int out_size, void* d_ws, size_t ws_size,
                              hipStream_t stream) {
  const float* x         = (const float*)d_in[0];
  const float* Wg        = (const float*)d_in[1];
  const float* bg        = (const float*)d_in[2];
  const float* W1        = (const float*)d_in[3];
  const float* b1        = (const float*)d_in[4];
  const float* ln_g      = (const float*)d_in[5];
  const float* ln_b      = (const float*)d_in[6];
  const float* W2        = (const float*)d_in[7];
  const float* b2        = (const float*)d_in[8];
  const float* res_scale = (const float*)d_in[9];
  float* out = (float*)d_out;

  char* ws = (char*)d_ws;
  unsigned short* W2b = (unsigned short*)(ws + 33554432);
  unsigned short* Xb  = (unsigned short*)(ws + 67108864);
  unsigned short* Hb  = (unsigned short*)(ws + 83886080);
  int* assign  = (int*)(ws + 117964800);
  int* ridx    = (int*)(ws + 117997568);
  int* ctrl    = (int*)(ws + 118030336);
  int* rank    = (int*)(ws + 118034432);
  int* blkcnt  = (int*)(ws + 118067200);
  int* blkoff  = (int*)(ws + 118068224);

  gate_kernel<<<TOK / 4, 256, 0, stream>>>(x, Wg, bg, assign);
  convert_kernel<<<2048, 256, 0, stream>>>(W2, W2b, NE * DIM * FF);
  count_rank_kernel<<<NBLK, 256, 0, stream>>>(assign, rank, blkcnt);
  scan2_kernel<<<1, 64, 0, stream>>>(ctrl, blkcnt, blkoff);
  gather_kernel<<<TOK, 256, 0, stream>>>(x, assign, rank, blkoff, ridx, Xb);
  gemm1_kernel<<<16 * MAXTILES, 512, 0, stream>>>(Xb, W1, b1, ctrl, Hb);
  ln_gelu_kernel<<<TOK, 256, 0, stream>>>(Hb, ln_g, ln_b, ctrl + 16);
  gemm2_kernel<<<8 * MAXTILES, 512, 0, stream>>>(Hb, W2b, b2, res_scale, ctrl, ridx, x, out);
}

// Round 16
// 264.625 us; speedup vs baseline: 1.0556x; 1.0556x over previous
//
#include <hip/hip_runtime.h>
#include <hip/hip_bf16.h>
#include <cstdint>
#include <cstddef>

#define TOK 8192
#define DIM 1024
#define FF  2048
#define NE  8
#define MAXTILES 72        // 128-row m-tile slots: 64 + 8 partials
#define NBLK 32            // count_rank blocks (256 tokens each)

typedef __attribute__((ext_vector_type(8))) short short8;
typedef __attribute__((ext_vector_type(4))) float f32x4;

__device__ inline void gload_lds16(const void* g, void* l) {
  __builtin_amdgcn_global_load_lds(
      (const __attribute__((address_space(1))) unsigned int*)g,
      (__attribute__((address_space(3))) unsigned int*)l, 16, 0, 0);
}

__device__ inline unsigned short f2bf(float f) {
  unsigned int u = __float_as_uint(f);
  u += 0x7fffu + ((u >> 16) & 1u);   // RNE
  return (unsigned short)(u >> 16);
}
__device__ inline float bf2f(unsigned short u) {
  return __uint_as_float(((unsigned int)u) << 16);
}
__device__ inline unsigned int cvt_pk_bf16(float a, float b) {  // lo=bf16(a), hi=bf16(b), RNE
  unsigned int r;
  asm("v_cvt_pk_bf16_f32 %0, %1, %2" : "=v"(r) : "v"(a), "v"(b));
  return r;
}

// ---------------- gating: logits, top-2 (highest index wins) -- no atomics ----------
__global__ __launch_bounds__(256) void gate_kernel(
    const float* __restrict__ x, const float* __restrict__ Wg,
    const float* __restrict__ bg, int* __restrict__ assign) {
  const int token = blockIdx.x * 4 + (threadIdx.x >> 6);
  const int lane = threadIdx.x & 63;
  if (token >= TOK) return;
  const float* xr = x + (size_t)token * DIM;
  float acc[NE];
#pragma unroll
  for (int e = 0; e < NE; ++e) acc[e] = 0.f;
#pragma unroll
  for (int i0 = 0; i0 < DIM; i0 += 256) {
    const int i = i0 + lane * 4;
    const float4 xv = *reinterpret_cast<const float4*>(xr + i);
#pragma unroll
    for (int e = 0; e < NE; ++e) {
      const float4 wv = *reinterpret_cast<const float4*>(Wg + e * DIM + i);
      acc[e] += xv.x * wv.x + xv.y * wv.y + xv.z * wv.z + xv.w * wv.w;
    }
  }
#pragma unroll
  for (int e = 0; e < NE; ++e) {
    float v = acc[e];
#pragma unroll
    for (int s = 32; s; s >>= 1) v += __shfl_xor(v, s);
    acc[e] = v + bg[e];
  }
  if (lane == 0) {
    float v1 = -INFINITY, v2 = -INFINITY; int i1 = 0, i2 = 0;
#pragma unroll
    for (int e = 0; e < NE; ++e) {
      const float v = acc[e];
      if (v > v1)      { v2 = v1; i2 = i1; v1 = v; i1 = e; }
      else if (v > v2) { v2 = v; i2 = e; }
    }
    assign[token] = (i1 > i2) ? i1 : i2;  // max(top2 indices); softmax-sum weight == 1.0
  }
}

// ---------------- ballot-based per-block counts + in-block ranks (no atomics) -------
__global__ __launch_bounds__(256) void count_rank_kernel(
    const int* __restrict__ assign, int* __restrict__ rank,
    int* __restrict__ blkcnt) {
  const int blk = blockIdx.x;
  const int tid = threadIdx.x;
  const int t = blk * 256 + tid;
  const int lane = tid & 63, wave = tid >> 6;
  const int a = assign[t];
  __shared__ int wcnt[4][NE];
  int myrank = 0;
#pragma unroll
  for (int e = 0; e < NE; ++e) {
    const unsigned long long m = __ballot(a == e);
    if (a == e) myrank = __popcll(m & ((1ull << lane) - 1ull));
    if (lane == 0) wcnt[wave][e] = __popcll(m);
  }
  __syncthreads();
  int pre = 0;
  for (int w = 0; w < wave; ++w) pre += wcnt[w][a];
  rank[t] = pre + myrank;
  if (tid < NE)
    blkcnt[blk * NE + tid] = wcnt[0][tid] + wcnt[1][tid] + wcnt[2][tid] + wcnt[3][tid];
}

// ---------------- scan: block offsets, expert offsets, 128-row tile table -----------
// ctrl: [16..24]=offsets, [25]=ntiles, [32..103]=tile_e, [128..199]=tile_m
__global__ void scan2_kernel(int* __restrict__ ctrl, const int* __restrict__ blkcnt,
                             int* __restrict__ blkoff) {
  const int tid = threadIdx.x;
  __shared__ int ecnt[NE];
  if (tid < NE) {
    int run = 0;
    for (int b = 0; b < NBLK; ++b) {
      blkoff[b * NE + tid] = run;
      run += blkcnt[b * NE + tid];
    }
    ecnt[tid] = run;
  }
  __syncthreads();
  if (tid == 0) {
    int s = 0, nt = 0;
#pragma unroll
    for (int e = 0; e < NE; ++e) {
      ctrl[16 + e] = s;
      const int cnt = ecnt[e];
      for (int m = 0; m * 128 < cnt && nt < MAXTILES; ++m) {
        ctrl[32 + nt] = e;  ctrl[128 + nt] = m;  ++nt;
      }
      s += cnt;
    }
    ctrl[24] = s;
    ctrl[25] = nt;
  }
  __syncthreads();
  if (tid < NE) {
    const int off = ctrl[16 + tid];
    for (int b = 0; b < NBLK; ++b) blkoff[b * NE + tid] += off;
  }
}

// ---------------- gather tokens into expert-contiguous bf16 rows (no atomics) -------
__global__ __launch_bounds__(256) void gather_kernel(
    const float* __restrict__ x, const int* __restrict__ assign,
    const int* __restrict__ rank, const int* __restrict__ blkoff,
    int* __restrict__ ridx, unsigned short* __restrict__ Xb) {
  const int token = blockIdx.x;
  const int a = assign[token];
  const int row = blkoff[(token >> 8) * NE + a] + rank[token];
  if (threadIdx.x == 0) ridx[row] = token;
  const int j = threadIdx.x * 4;
  const float4 v = *reinterpret_cast<const float4*>(x + (size_t)token * DIM + j);
  ushort4 o;
  o.x = f2bf(v.x); o.y = f2bf(v.y); o.z = f2bf(v.z); o.w = f2bf(v.w);
  *reinterpret_cast<ushort4*>(Xb + (size_t)row * DIM + j) = o;
}

// ================= grouped GEMM1: H = Xb @ W1e^T + b1 (bf16 out) =====================
// r12 form + junk-restage skip. 128x128xBK64, 512 thr / 8 waves (2Mx4N). A: bf16
// gload_lds dbuf. B: fp32 W1 reg-staged + fused cvt_pk->bf16 + swizzled ds_write.
__global__ __launch_bounds__(512) void gemm1_kernel(
    const unsigned short* __restrict__ Xb, const float* __restrict__ W1,
    const float* __restrict__ b1, const int* __restrict__ ctrl,
    unsigned short* __restrict__ Hb) {
  const int b = blockIdx.x;
  const int lid = (b & 7) * (16 * MAXTILES / 8) + (b >> 3);  // XCD-chunked, bijective
  const int nx = lid / MAXTILES;            // ti-fastest: same-XCD blocks share B panels
  const int ti = lid % MAXTILES;
  if (ti >= ctrl[25]) return;
  const int e = ctrl[32 + ti];
  const int m_tile = ctrl[128 + ti];
  const int base = ctrl[16 + e];
  const int count = ctrl[17 + e] - base;
  const int n0 = nx * 128;
  constexpr int K = DIM, NT = DIM / 64;
  __shared__ unsigned short As[2][8192];    // 2 x 16KB
  __shared__ unsigned short Bs[8192];       // 16KB (single: write/read barrier-separated)
  const int tid = threadIdx.x;
  const int wave = tid >> 6, lane = tid & 63;
  const int wm = wave >> 2, wn = wave & 3;
  const int l15 = lane & 15, l7 = lane & 7, jb = lane >> 4, arow = lane >> 3;
  const int acolS = (l7 ^ arow) * 8;        // A pre-swizzled source col (T2 + rule#21)
  f32x4 acc[4][2] = {};
  const unsigned short* Ag = Xb + (size_t)(base + m_tile * 128) * K;
  const float* Bg = W1 + ((size_t)e * FF + n0) * K;
  const int maxr = (TOK - 1) - (base + m_tile * 128);
  const int c0 = tid, c1 = tid + 512;
  const int r0 = c0 >> 3, j0 = c0 & 7, r1 = c1 >> 3, j1 = c1 & 7;
  const int wr0 = (r0 * 64 + (j0 ^ (r0 & 7)) * 8);   // swizzled LDS dest (shorts)
  const int wr1 = (r1 * 64 + (j1 ^ (r1 & 7)) * 8);
  const float* bp0 = Bg + (size_t)r0 * K + j0 * 8;
  const float* bp1 = Bg + (size_t)r1 * K + j1 * 8;
  float4 br0[4], br1[4];                     // 2 reg sets, ping-pong (static idx)

  auto gloadA = [&](int buf, int t) {
#pragma unroll
    for (int it = 0; it < 2; ++it) {
      const int c = it * 8 + wave;
      int r = c * 8 + arow; if (r > maxr) r = maxr;
      gload_lds16(Ag + (size_t)r * K + t * 64 + acolS, &As[buf][c * 512]);
    }
  };
  auto loadB = [&](float4 (&br)[4], int t) {
    br[0] = *reinterpret_cast<const float4*>(bp0 + t * 64);
    br[1] = *reinterpret_cast<const float4*>(bp0 + t * 64 + 4);
    br[2] = *reinterpret_cast<const float4*>(bp1 + t * 64);
    br[3] = *reinterpret_cast<const float4*>(bp1 + t * 64 + 4);
  };
  auto writeB = [&](float4 (&br)[4]) {
    uint4 p;
    p.x = cvt_pk_bf16(br[0].x, br[0].y); p.y = cvt_pk_bf16(br[0].z, br[0].w);
    p.z = cvt_pk_bf16(br[1].x, br[1].y); p.w = cvt_pk_bf16(br[1].z, br[1].w);
    *reinterpret_cast<uint4*>(&Bs[wr0]) = p;
    p.x = cvt_pk_bf16(br[2].x, br[2].y); p.y = cvt_pk_bf16(br[2].z, br[2].w);
    p.z = cvt_pk_bf16(br[3].x, br[3].y); p.w = cvt_pk_bf16(br[3].z, br[3].w);
    *reinterpret_cast<uint4*>(&Bs[wr1]) = p;
  };
  auto compute = [&](int buf) {
#pragma unroll
    for (int kk = 0; kk < 64; kk += 32) {
      short8 a[4], bb[2];
      const int js = (((kk >> 3) + jb) ^ l7) << 3;
#pragma unroll
      for (int i = 0; i < 4; ++i)
        a[i] = *reinterpret_cast<const short8*>(&As[buf][(wm * 64 + i * 16 + l15) * 64 + js]);
#pragma unroll
      for (int j = 0; j < 2; ++j)
        bb[j] = *reinterpret_cast<const short8*>(&Bs[(wn * 32 + j * 16 + l15) * 64 + js]);
#pragma unroll
      for (int i = 0; i < 4; ++i)
#pragma unroll
        for (int j = 0; j < 2; ++j)
          acc[i][j] = __builtin_amdgcn_mfma_f32_16x16x32_bf16(a[i], bb[j], acc[i][j], 0, 0, 0);
    }
  };
  // phase: stage B(t) from brC (auto-waited), optionally issue A(t1)/B(t1) prefetch,
  // counted wait, publish, compute(buf). Last phase skips prefetch (saves ~48KB junk
  // traffic per block; vmcnt(6) with fewer outstanding loads is a no-op -> safe).
  auto phase = [&](float4 (&brC)[4], float4 (&brN)[4], int buf, int t) {
    const bool pf = (t + 1 < NT);
    const int t1 = pf ? t + 1 : 0;
    if (pf) gloadA(buf ^ 1, t1);
    writeB(brC);
    if (pf) loadB(brN, t1);
    asm volatile("s_waitcnt vmcnt(6) lgkmcnt(0)" ::: "memory");
    __builtin_amdgcn_sched_barrier(0);
    __builtin_amdgcn_s_barrier();
    __builtin_amdgcn_sched_barrier(0);
    compute(buf);
    __builtin_amdgcn_sched_barrier(0);
    __builtin_amdgcn_s_barrier();
    __builtin_amdgcn_sched_barrier(0);
  };

  loadB(br0, 0);        // queue: B(0)x4 ...
  gloadA(0, 0);         // ... then A(0)x2
#pragma unroll 1
  for (int t = 0; t < NT; t += 2) {
    phase(br0, br1, 0, t);
    phase(br1, br0, 1, t + 1);
  }

  const float* b1e = b1 + (size_t)e * FF;
  const int rbase = m_tile * 128 + wm * 64 + (lane >> 4) * 4;
  const int cbase = n0 + wn * 32 + l15;
#pragma unroll
  for (int i = 0; i < 4; ++i) {
#pragma unroll
    for (int j = 0; j < 2; ++j) {
      const int col = cbase + j * 16;
      const float bias = b1e[col];
#pragma unroll
      for (int r = 0; r < 4; ++r) {
        const int lr = rbase + i * 16 + r;
        if (lr < count)
          Hb[(size_t)(base + lr) * FF + col] = f2bf(acc[i][j][r] + bias);
      }
    }
  }
}

// ---------------- LayerNorm + exact GELU, in place on Hb ----------------
__global__ __launch_bounds__(256) void ln_gelu_kernel(
    unsigned short* __restrict__ Hb, const float* __restrict__ ln_g,
    const float* __restrict__ ln_b, const int* __restrict__ offsets) {
  const int row = blockIdx.x;
  int e = 0;
#pragma unroll
  for (int i = 1; i < NE; ++i) e += (row >= offsets[i]) ? 1 : 0;
  unsigned short* h = Hb + (size_t)row * FF;
  const int tid = threadIdx.x;
  const int lane = tid & 63, wave = tid >> 6;
  float v[8];
  float sum = 0.f, sq = 0.f;
  short8 raw = *reinterpret_cast<const short8*>(h + tid * 8);
#pragma unroll
  for (int i = 0; i < 8; ++i) {
    v[i] = bf2f((unsigned short)raw[i]);
    sum += v[i]; sq += v[i] * v[i];
  }
#pragma unroll
  for (int s = 32; s; s >>= 1) { sum += __shfl_xor(sum, s); sq += __shfl_xor(sq, s); }
  __shared__ float red[8];
  if (lane == 0) { red[wave] = sum; red[wave + 4] = sq; }
  __syncthreads();
  sum = red[0] + red[1] + red[2] + red[3];
  sq  = red[4] + red[5] + red[6] + red[7];
  const float mu = sum * (1.f / FF);
  const float var = sq * (1.f / FF) - mu * mu;
  const float rstd = rsqrtf(var + 1e-5f);
  const float* ge = ln_g + (size_t)e * FF + tid * 8;
  const float* be = ln_b + (size_t)e * FF + tid * 8;
  short8 outv;
#pragma unroll
  for (int i = 0; i < 8; ++i) {
    const float t = (v[i] - mu) * rstd * ge[i] + be[i];
    const float g = 0.5f * t * (1.f + erff(t * 0.70710678118f));
    outv[i] = (short)f2bf(g);
  }
  *reinterpret_cast<short8*>(h + tid * 8) = outv;
}

// ================= grouped GEMM2: out[t] = (Hb @ W2e^T + b2)*se + x[t] ===============
// r12 form + junk-restage skip; A=Hb bf16 gload_lds dbuf, B=W2 fp32 fused-convert.
__global__ __launch_bounds__(512) void gemm2_kernel(
    const unsigned short* __restrict__ Hb, const float* __restrict__ W2,
    const float* __restrict__ b2, const float* __restrict__ res_scale,
    const int* __restrict__ ctrl, const int* __restrict__ ridx,
    const float* __restrict__ x, float* __restrict__ out) {
  const int b = blockIdx.x;
  const int lid = (b & 7) * MAXTILES + (b >> 3);   // grid 8*MAXTILES
  const int nx = lid / MAXTILES;
  const int ti = lid % MAXTILES;
  if (ti >= ctrl[25]) return;
  const int e = ctrl[32 + ti];
  const int m_tile = ctrl[128 + ti];
  const int base = ctrl[16 + e];
  const int count = ctrl[17 + e] - base;
  const int n0 = nx * 128;
  constexpr int K = FF, NT = FF / 64;
  __shared__ unsigned short As[2][8192];
  __shared__ unsigned short Bs[8192];
  const int tid = threadIdx.x;
  const int wave = tid >> 6, lane = tid & 63;
  const int wm = wave >> 2, wn = wave & 3;
  const int l15 = lane & 15, l7 = lane & 7, jb = lane >> 4, arow = lane >> 3;
  const int acolS = (l7 ^ arow) * 8;
  f32x4 acc[4][2] = {};
  const unsigned short* Ag = Hb + (size_t)(base + m_tile * 128) * K;
  const float* Bg = W2 + ((size_t)e * DIM + n0) * K;
  const int maxr = (TOK - 1) - (base + m_tile * 128);
  const int c0 = tid, c1 = tid + 512;
  const int r0 = c0 >> 3, j0 = c0 & 7, r1 = c1 >> 3, j1 = c1 & 7;
  const int wr0 = (r0 * 64 + (j0 ^ (r0 & 7)) * 8);
  const int wr1 = (r1 * 64 + (j1 ^ (r1 & 7)) * 8);
  const float* bp0 = Bg + (size_t)r0 * K + j0 * 8;
  const float* bp1 = Bg + (size_t)r1 * K + j1 * 8;
  float4 br0[4], br1[4];

  auto gloadA = [&](int buf, int t) {
#pragma unroll
    for (int it = 0; it < 2; ++it) {
      const int c = it * 8 + wave;
      int r = c * 8 + arow; if (r > maxr) r = maxr;
      gload_lds16(Ag + (size_t)r * K + t * 64 + acolS, &As[buf][c * 512]);
    }
  };
  auto loadB = [&](float4 (&br)[4], int t) {
    br[0] = *reinterpret_cast<const float4*>(bp0 + t * 64);
    br[1] = *reinterpret_cast<const float4*>(bp0 + t * 64 + 4);
    br[2] = *reinterpret_cast<const float4*>(bp1 + t * 64);
    br[3] = *reinterpret_cast<const float4*>(bp1 + t * 64 + 4);
  };
  auto writeB = [&](float4 (&br)[4]) {
    uint4 p;
    p.x = cvt_pk_bf16(br[0].x, br[0].y); p.y = cvt_pk_bf16(br[0].z, br[0].w);
    p.z = cvt_pk_bf16(br[1].x, br[1].y); p.w = cvt_pk_bf16(br[1].z, br[1].w);
    *reinterpret_cast<uint4*>(&Bs[wr0]) = p;
    p.x = cvt_pk_bf16(br[2].x, br[2].y); p.y = cvt_pk_bf16(br[2].z, br[2].w);
    p.z = cvt_pk_bf16(br[3].x, br[3].y); p.w = cvt_pk_bf16(br[3].z, br[3].w);
    *reinterpret_cast<uint4*>(&Bs[wr1]) = p;
  };
  auto compute = [&](int buf) {
#pragma unroll
    for (int kk = 0; kk < 64; kk += 32) {
      short8 a[4], bb[2];
      const int js = (((kk >> 3) + jb) ^ l7) << 3;
#pragma unroll
      for (int i = 0; i < 4; ++i)
        a[i] = *reinterpret_cast<const short8*>(&As[buf][(wm * 64 + i * 16 + l15) * 64 + js]);
#pragma unroll
      for (int j = 0; j < 2; ++j)
        bb[j] = *reinterpret_cast<const short8*>(&Bs[(wn * 32 + j * 16 + l15) * 64 + js]);
#pragma unroll
      for (int i = 0; i < 4; ++i)
#pragma unroll
        for (int j = 0; j < 2; ++j)
          acc[i][j] = __builtin_amdgcn_mfma_f32_16x16x32_bf16(a[i], bb[j], acc[i][j], 0, 0, 0);
    }
  };
  auto phase = [&](float4 (&brC)[4], float4 (&brN)[4], int buf, int t) {
    const bool pf = (t + 1 < NT);
    const int t1 = pf ? t + 1 : 0;
    if (pf) gloadA(buf ^ 1, t1);
    writeB(brC);
    if (pf) loadB(brN, t1);
    asm volatile("s_waitcnt vmcnt(6) lgkmcnt(0)" ::: "memory");
    __builtin_amdgcn_sched_barrier(0);
    __builtin_amdgcn_s_barrier();
    __builtin_amdgcn_sched_barrier(0);
    compute(buf);
    __builtin_amdgcn_sched_barrier(0);
    __builtin_amdgcn_s_barrier();
    __builtin_amdgcn_sched_barrier(0);
  };

  loadB(br0, 0);
  gloadA(0, 0);
#pragma unroll 1
  for (int t = 0; t < NT; t += 2) {
    phase(br0, br1, 0, t);
    phase(br1, br0, 1, t + 1);
  }

  const float* b2e = b2 + (size_t)e * DIM;
  const float se = res_scale[e];
  const int rbase = m_tile * 128 + wm * 64 + (lane >> 4) * 4;
  const int cbase = n0 + wn * 32 + l15;
#pragma unroll
  for (int i = 0; i < 4; ++i) {
#pragma unroll
    for (int r = 0; r < 4; ++r) {
      const int lr = rbase + i * 16 + r;
      if (lr < count) {
        const int trow = ridx[base + lr];
        const float* xrow = x + (size_t)trow * DIM;
        float* orow = out + (size_t)trow * DIM;
#pragma unroll
        for (int j = 0; j < 2; ++j) {
          const int col = cbase + j * 16;
          orow[col] = (acc[i][j][r] + b2e[col]) * se + xrow[col];
        }
      }
    }
  }
}

extern "C" void kernel_launch(void* const* d_in, const int* in_sizes, int n_in,
                              void* d_out, int out_size, void* d_ws, size_t ws_size,
                              hipStream_t stream) {
  const float* x         = (const float*)d_in[0];
  const float* Wg        = (const float*)d_in[1];
  const float* bg        = (const float*)d_in[2];
  const float* W1        = (const float*)d_in[3];
  const float* b1        = (const float*)d_in[4];
  const float* ln_g      = (const float*)d_in[5];
  const float* ln_b      = (const float*)d_in[6];
  const float* W2        = (const float*)d_in[7];
  const float* b2        = (const float*)d_in[8];
  const float* res_scale = (const float*)d_in[9];
  float* out = (float*)d_out;

  char* ws = (char*)d_ws;
  unsigned short* Xb  = (unsigned short*)(ws + 67108864);
  unsigned short* Hb  = (unsigned short*)(ws + 83886080);
  int* assign  = (int*)(ws + 117964800);
  int* ridx    = (int*)(ws + 117997568);
  int* ctrl    = (int*)(ws + 118030336);
  int* rank    = (int*)(ws + 118034432);
  int* blkcnt  = (int*)(ws + 118067200);
  int* blkoff  = (int*)(ws + 118068224);

  gate_kernel<<<TOK / 4, 256, 0, stream>>>(x, Wg, bg, assign);
  count_rank_kernel<<<NBLK, 256, 0, stream>>>(assign, rank, blkcnt);
  scan2_kernel<<<1, 64, 0, stream>>>(ctrl, blkcnt, blkoff);
  gather_kernel<<<TOK, 256, 0, stream>>>(x, assign, rank, blkoff, ridx, Xb);
  gemm1_kernel<<<16 * MAXTILES, 512, 0, stream>>>(Xb, W1, b1, ctrl, Hb);
  ln_gelu_kernel<<<TOK, 256, 0, stream>>>(Hb, ln_g, ln_b, ctrl + 16);
  gemm2_kernel<<<8 * MAXTILES, 512, 0, stream>>>(Hb, W2, b2, res_scale, ctrl, ridx, x, out);
}